// Round 11
// baseline (194.609 us; speedup 1.0000x reference)
//
#include <hip/hip_runtime.h>
#include <hip/hip_bf16.h>
#include <cstdint>

// Problem constants (reference: N=16384, F=1024, H=256)
#define NR 16384
#define NF 1024
#define NH 256

typedef __bf16 bf16x8 __attribute__((ext_vector_type(8)));
typedef float f32x4 __attribute__((ext_vector_type(4)));
typedef unsigned short us8 __attribute__((ext_vector_type(8)));

static __device__ __forceinline__ unsigned short f2bf(float f) {
    unsigned u = __float_as_uint(f);
    u += 0x7FFFu + ((u >> 16) & 1u);   // RNE
    return (unsigned short)(u >> 16);
}

// Fragment-major packed weights (1 KB per cell = 64 lanes x 16 B):
//   Wepk[nb=16][kc=32][lane=q*16+n][e=8] = bf16(We[kc*32+q*8+e][nb*16+n])
//   Wdpk[nb=64][kc= 8][lane=q*16+n][e=8] = bf16(Wd[kc*32+q*8+e][nb*16+n])
// hdr: [0..63] mse cells, [64..127] pair cells, [128] pair ticket,
//      [129] nP (int), [130] nR (int)

// ---------------------------------------------------------------------------
// prep: coalesced packing (unchanged). 256 blocks x 256 thr.
// ---------------------------------------------------------------------------
__global__ __launch_bounds__(256) void prep_kernel(
    const float* __restrict__ We, const float* __restrict__ Wd,
    unsigned short* __restrict__ Wepk, unsigned short* __restrict__ Wdpk,
    float* __restrict__ hdr) {
    const int b = blockIdx.x, t = threadIdx.x;
    if (b == 0 && t < 192) hdr[t] = 0.f;
    if (b < 128) {
        const int k0 = b, c = t;                       // k rows 8*k0..8*k0+7
        const int kc = k0 >> 2, q = k0 & 3, nb = c >> 4, li = c & 15;
        us8 v;
#pragma unroll
        for (int e = 0; e < 8; e++)
            v[e] = f2bf(We[(size_t)(k0 * 8 + e) * NH + c]);
        *(us8*)&Wepk[((size_t)(nb * 32 + kc)) * 512 + (q * 16 + li) * 8] = v;
    } else {
        const int idx = b - 128;
        const int k0 = idx >> 2, c = (idx & 3) * 256 + t;
        const int kc = k0 >> 2, q = k0 & 3, nb = c >> 4, li = c & 15;
        us8 v;
#pragma unroll
        for (int e = 0; e < 8; e++)
            v[e] = f2bf(Wd[(size_t)(k0 * 8 + e) * NF + c]);
        *(us8*)&Wdpk[((size_t)(nb * 8 + kc)) * 512 + (q * 16 + li) * 8] = v;
    }
}

// ---------------------------------------------------------------------------
// FUSED (R10): grid 256 x 512 thr (8 waves), 64 m-rows/block.
// R10 changes vs R9 (53us; R9 was a NULL result — conflicts/VGPR/spill all
// unchanged):
// (a) __launch_bounds__(512,1): R9's (512,2) behaved as 2-blocks/CU CUDA
//     semantics -> 128-VGPR cap -> 9.3MB scratch spill in both R5 and R9.
//     (512,1) -> 8 waves/CU -> 256-VGPR budget -> no spill.
// (b) DOUBLE-BUFFERED xa (2x32KB): quarter k+1 staged into the dead buffer;
//     ONE barrier per quarter (was two). The ds_write's vmcnt wait now
//     overlaps MFMA instead of serializing behind a read-drain barrier.
// (c) T14 on the MSE X re-read: all 16 float4 X loads per pass issued
//     BEFORE the phase-2 MFMA loop (L3 latency hides under MFMA).
// Accumulation order identical -> bitwise-same output.
// NOTE (R9 lesson): SQ_LDS_BANK_CONFLICT ~8-9M is inherent b128 multi-cycle
// counting + minor 4-way writes, NOT a fixable read-serialization term.
// ---------------------------------------------------------------------------
__global__ __launch_bounds__(512, 1) void fused_kernel(
    const float* __restrict__ X,
    const unsigned short* __restrict__ Wepk, const unsigned short* __restrict__ Wdpk,
    const float* __restrict__ be, const float* __restrict__ bd,
    const float* __restrict__ Wc, const int* __restrict__ s, const int* __restrict__ pv,
    float* __restrict__ cP, float* __restrict__ cR, float* __restrict__ hdr) {
    __shared__ union {
        unsigned short xa[2][16384];     // 2 x 32 KB: X quarters, fragment-major
        struct {
            unsigned short gs[16384];    // 32 KB: g tile, fragment-major
            float credu[8][64];
            float msred[8];
        } p2;
    } u;
    const int t = threadIdx.x;
    const int b = blockIdx.x, m0 = b * 64;
    const int w = t >> 6, lane = t & 63, q = lane >> 4, li = lane & 15;

    // staging geometry: wave w stages rows w*8..w*8+7; lane reads 16B at
    // col lane*4 (global contiguous 1KB per wave-row).
    // LDS cell (kcgl = lane>>3, mi = r>>4); slot s = sq2*16+(r&15), p = s^kcgl.
    const int srow = w * 8;
    const int kcgl = lane >> 3;          // cell k-col 0..7
    const int sq2  = (lane >> 1) & 3;    // fragment q of this 16B
    const int sh   = lane & 1;           // element half

    // ---------------- stage quarter 0 into buffer 0 ------------------------
    {
        const float* xq = X + (size_t)m0 * NF + lane * 4;
#pragma unroll
        for (int rr = 0; rr < 8; ++rr) {
            const int r = srow + rr;
            float4 v4 = *(const float4*)(xq + (size_t)r * NF);
            ushort4 st = { f2bf(v4.x), f2bf(v4.y), f2bf(v4.z), f2bf(v4.w) };
            const int p = (sq2 * 16 + (r & 15)) ^ kcgl;
            *(ushort4*)&u.xa[0][(kcgl * 4 + (r >> 4)) * 512 + p * 8 + sh * 4] = st;
        }
    }
    __syncthreads();

    // ---------------- phase 1: X @ We (8-deep B prefetch, dbuf) -------------
    const unsigned short* Bp[2];
#pragma unroll
    for (int j = 0; j < 2; j++)
        Bp[j] = Wepk + ((size_t)(w * 2 + j) * 32) * 512 + lane * 8;

    us8 fb[8][2];
#pragma unroll
    for (int z = 0; z < 8; ++z)
#pragma unroll
        for (int j = 0; j < 2; j++) fb[z][j] = *(const us8*)(Bp[j] + z * 512);

    f32x4 acc[4][2] = {};

#pragma unroll
    for (int ks = 0; ks < 4; ++ks) {
        const int cur = ks & 1;
        float4 xn[8];
        // T14 issue-early: next quarter's X loads (independent of this qtr)
        if (ks < 3) {
#pragma unroll
            for (int rr = 0; rr < 8; ++rr)
                xn[rr] = *(const float4*)(X + (size_t)(m0 + srow + rr) * NF +
                                          (ks + 1) * 256 + lane * 4);
        }
#pragma unroll
        for (int kcl = 0; kcl < 8; ++kcl) {
            const int kcg = ks * 8 + kcl;
            const int cb = kcg & 7;
            bf16x8 a[4];
#pragma unroll
            for (int mi = 0; mi < 4; ++mi)
                a[mi] = __builtin_bit_cast(bf16x8,
                    *(const us8*)&u.xa[cur][(kcl * 4 + mi) * 512 + (lane ^ kcl) * 8]);
#pragma unroll
            for (int j = 0; j < 2; ++j) {
                bf16x8 bf = __builtin_bit_cast(bf16x8, fb[cb][j]);
#pragma unroll
                for (int mi = 0; mi < 4; ++mi)
                    acc[mi][j] = __builtin_amdgcn_mfma_f32_16x16x32_bf16(bf, a[mi], acc[mi][j], 0, 0, 0);
            }
            if (kcg + 8 < 32) {
#pragma unroll
                for (int j = 0; j < 2; j++) fb[cb][j] = *(const us8*)(Bp[j] + (kcg + 8) * 512);
            }
        }
        // write-late into the DEAD buffer (last read 2 quarters ago) — no
        // read-drain barrier needed before this write.
        if (ks < 3) {
#pragma unroll
            for (int rr = 0; rr < 8; ++rr) {
                const int r = srow + rr;
                ushort4 st = { f2bf(xn[rr].x), f2bf(xn[rr].y),
                               f2bf(xn[rr].z), f2bf(xn[rr].w) };
                const int p = (sq2 * 16 + (r & 15)) ^ kcgl;
                *(ushort4*)&u.xa[cur ^ 1][(kcgl * 4 + (r >> 4)) * 512 + p * 8 + sh * 4] = st;
            }
        }
        __syncthreads();          // one barrier per quarter
    }

    // epilogue: g -> fragment-major gs + critic partials (gs = xa[0], dead;
    // credu spills into xa[1] head, also dead after the ks=3 barrier)
#pragma unroll
    for (int mi = 0; mi < 4; ++mi) {
        float csum = 0.f;
#pragma unroll
        for (int j = 0; j < 2; ++j) {
            const int colb = w * 32 + j * 16 + q * 4;
            float4 be4 = *(const float4*)&be[colb];
            float4 wc4 = *(const float4*)&Wc[colb];
            float v0 = acc[mi][j][0] + be4.x;
            float v1 = acc[mi][j][1] + be4.y;
            float v2 = acc[mi][j][2] + be4.z;
            float v3 = acc[mi][j][3] + be4.w;
            csum += v0 * wc4.x + v1 * wc4.y + v2 * wc4.z + v3 * wc4.w;
            ushort4 st = { f2bf(v0), f2bf(v1), f2bf(v2), f2bf(v3) };
            const int q2e = j * 2 + (q >> 1);
            const int p = (q2e * 16 + li) ^ w;
            *(ushort4*)&u.p2.gs[(w * 4 + mi) * 512 + p * 8 + (q & 1) * 4] = st;
        }
        csum += __shfl_down(csum, 32);
        csum += __shfl_down(csum, 16);
        if (lane < 16) u.p2.credu[w][mi * 16 + lane] = csum;
    }
    __syncthreads();   // gs + credu ready

    // in-block compaction of this block's 64 critic values (wave 0)
    if (t < 64) {
        float cs = 0.f;
#pragma unroll
        for (int ww = 0; ww < 8; ++ww) cs += u.p2.credu[ww][t];
        bool pr = (s[m0 + t] == pv[0]);
        unsigned long long mk = __ballot(pr);
        int np = __popcll(mk);
        int baseP = 0, baseR = 0;
        if (t == 0) {
            baseP = atomicAdd((int*)hdr + 129, np);
            baseR = atomicAdd((int*)hdr + 130, 64 - np);
        }
        baseP = __shfl(baseP, 0);
        baseR = __shfl(baseR, 0);
        int offP = __popcll(mk & ((1ull << t) - 1ull));
        int offR = t - offP;
        if (pr) cP[baseP + offP] = cs; else cR[baseR + offR] = cs;
    }

    // ---------------- phase 2: g @ Wd + MSE (2 passes x 512 cols) -----------
    float lsum = 0.f;
    const unsigned short* Wp = Wdpk + lane * 8;
#pragma unroll
    for (int pass = 0; pass < 2; ++pass) {
        const int nb0 = pass * 32 + w * 4;     // 4 n-blocks of 16 per wave
        us8 gb[4][4];
#pragma unroll
        for (int z = 0; z < 4; ++z)
#pragma unroll
            for (int j = 0; j < 4; ++j)
                gb[z][j] = *(const us8*)(Wp + ((size_t)((nb0 + j) * 8 + z)) * 512);
        // T14 issue-early: this pass's X re-read (independent of MFMA chain)
        float4 xr[4][4];
#pragma unroll
        for (int mi = 0; mi < 4; ++mi) {
            const size_t rowoff = (size_t)(m0 + mi * 16 + li) * NF;
#pragma unroll
            for (int j = 0; j < 4; ++j)
                xr[mi][j] = *(const float4*)&X[rowoff + pass * 512 + w * 64 + j * 16 + q * 4];
        }
        f32x4 a2[4][4] = {};
#pragma unroll
        for (int kc = 0; kc < 8; ++kc) {
            const int cb = kc & 3;
            bf16x8 af[4];
#pragma unroll
            for (int mi = 0; mi < 4; ++mi)
                af[mi] = __builtin_bit_cast(bf16x8,
                    *(const us8*)&u.p2.gs[(kc * 4 + mi) * 512 + (lane ^ kc) * 8]);
#pragma unroll
            for (int j = 0; j < 4; ++j) {
                bf16x8 bf = __builtin_bit_cast(bf16x8, gb[cb][j]);
#pragma unroll
                for (int mi = 0; mi < 4; ++mi)
                    a2[mi][j] = __builtin_amdgcn_mfma_f32_16x16x32_bf16(bf, af[mi], a2[mi][j], 0, 0, 0);
            }
            if (kc + 4 < 8) {
#pragma unroll
                for (int j = 0; j < 4; ++j)
                    gb[cb][j] = *(const us8*)(Wp + ((size_t)((nb0 + j) * 8 + kc + 4)) * 512);
            }
        }
        // MSE epilogue for this 512-col pass
#pragma unroll
        for (int mi = 0; mi < 4; ++mi) {
#pragma unroll
            for (int j = 0; j < 4; ++j) {
                const int colb = pass * 512 + w * 64 + j * 16 + q * 4;
                float4 bd4 = *(const float4*)&bd[colb];
                float d0 = a2[mi][j][0] + bd4.x - xr[mi][j].x;
                float d1 = a2[mi][j][1] + bd4.y - xr[mi][j].y;
                float d2 = a2[mi][j][2] + bd4.z - xr[mi][j].z;
                float d3 = a2[mi][j][3] + bd4.w - xr[mi][j].w;
                lsum += d0 * d0 + d1 * d1 + d2 * d2 + d3 * d3;
            }
        }
    }
#pragma unroll
    for (int o = 32; o; o >>= 1) lsum += __shfl_down(lsum, o);
    if (lane == 0) u.p2.msred[w] = lsum;
    __syncthreads();
    if (t == 0) {
        float ms = 0.f;
#pragma unroll
        for (int ww = 0; ww < 8; ++ww) ms += u.p2.msred[ww];
        atomicAdd(&hdr[b & 63], ms);
    }
}

// ---------------------------------------------------------------------------
// compacted pairwise L1 + fused finalize (last-ticket block writes d_out)
// grid (16 j-chunks x 32 i-chunks of 512)
// ---------------------------------------------------------------------------
__global__ __launch_bounds__(256) void pair_fin_kernel(
    const float* __restrict__ cP, const float* __restrict__ cR,
    float* __restrict__ hdr, float* __restrict__ out) {
    __shared__ float sj[1024];
    __shared__ float red[256];
    __shared__ int win;
    const int nP = ((const int*)hdr)[129];
    const int nR = ((const int*)hdr)[130];
    const int jb = blockIdx.x * 1024;
    int jn = nR - jb; if (jn < 0) jn = 0; if (jn > 1024) jn = 1024;
    float sum = 0.f;
    if (jn > 0 && blockIdx.y * 512 < nP) {
        for (int j = threadIdx.x; j < 1024; j += 256)
            sj[j] = (jb + j < nR) ? cR[jb + j] : 0.f;
        __syncthreads();
        const int a0 = blockIdx.y * 512 + threadIdx.x, a1 = a0 + 256;
        const float ca0 = (a0 < nP) ? cP[a0] : 0.f;
        const float ca1 = (a1 < nP) ? cP[a1] : 0.f;
        float s0 = 0.f, s1 = 0.f;
#pragma unroll 8
        for (int j4 = 0; j4 < 256; j4++) {
            float4 v = *(const float4*)&sj[j4 * 4];
            s0 += fabsf(ca0 - v.x) + fabsf(ca0 - v.y) + fabsf(ca0 - v.z) + fabsf(ca0 - v.w);
            s1 += fabsf(ca1 - v.x) + fabsf(ca1 - v.y) + fabsf(ca1 - v.z) + fabsf(ca1 - v.w);
        }
        float pad = (float)(1024 - jn);
        s0 -= pad * fabsf(ca0);
        s1 -= pad * fabsf(ca1);
        if (a0 >= nP) s0 = 0.f;
        if (a1 >= nP) s1 = 0.f;
        sum = s0 + s1;
#pragma unroll
        for (int o = 32; o; o >>= 1) sum += __shfl_down(sum, o);
        if ((threadIdx.x & 63) == 0 && sum != 0.f)
            atomicAdd(&hdr[64 + ((blockIdx.y * 16 + blockIdx.x) & 63)], sum);
    }
    __threadfence();
    __syncthreads();
    if (threadIdx.x == 0)
        win = (atomicAdd((int*)(hdr + 128), 1) == 16 * 32 - 1) ? 1 : 0;
    __syncthreads();
    if (win) {
        float v = (threadIdx.x < 128) ? atomicAdd(&hdr[threadIdx.x], 0.f) : 0.f;
        red[threadIdx.x] = v;
        __syncthreads();
        if (threadIdx.x == 0) {
            float ms = 0.f, ps = 0.f;
            for (int i = 0; i < 64; i++) { ms += red[i]; ps += red[64 + i]; }
            int np = atomicAdd((int*)(hdr + 129), 0);
            out[0] = ms / (float)((size_t)NR * NF);
            out[1] = (float)NR;
            out[2] = ps / (float)np;
            out[3] = (float)np;
        }
    }
}

extern "C" void kernel_launch(void* const* d_in, const int* in_sizes, int n_in,
                              void* d_out, int out_size, void* d_ws, size_t ws_size,
                              hipStream_t stream) {
    const float* X  = (const float*)d_in[0];
    const float* We = (const float*)d_in[1];
    const float* be = (const float*)d_in[2];
    const float* Wd = (const float*)d_in[3];
    const float* bd = (const float*)d_in[4];
    const float* Wc = (const float*)d_in[5];
    // bc (d_in[6]) omitted: cancels in |c_i - c_j|
    const int*   s  = (const int*)d_in[7];
    const int*   pv = (const int*)d_in[8];

    char* ws = (char*)d_ws;
    float* hdr = (float*)ws;                                     // 192 f
    float* cP  = (float*)(ws + 1024);                            // 64 KB
    float* cR  = (float*)(ws + 1024 + 65536);                    // 64 KB
    unsigned short* Wepk = (unsigned short*)(ws + 1024 + 2 * 65536);  // 512 KB
    unsigned short* Wdpk = Wepk + (size_t)NH * NF;                    // 512 KB

    prep_kernel<<<256, 256, 0, stream>>>(We, Wd, Wepk, Wdpk, hdr);
    fused_kernel<<<256, 512, 0, stream>>>(X, Wepk, Wdpk, be, bd, Wc, s, pv, cP, cR, hdr);
    pair_fin_kernel<<<dim3(16, 32), 256, 0, stream>>>(cP, cR, hdr, (float*)d_out);
}

// Round 12
// 177.630 us; speedup vs baseline: 1.0956x; 1.0956x over previous
//
#include <hip/hip_runtime.h>
#include <hip/hip_bf16.h>
#include <cstdint>

// Problem constants (reference: N=16384, F=1024, H=256)
#define NR 16384
#define NF 1024
#define NH 256

typedef __bf16 bf16x8 __attribute__((ext_vector_type(8)));
typedef float f32x4 __attribute__((ext_vector_type(4)));
typedef unsigned short us8 __attribute__((ext_vector_type(8)));

static __device__ __forceinline__ unsigned short f2bf(float f) {
    unsigned u = __float_as_uint(f);
    u += 0x7FFFu + ((u >> 16) & 1u);   // RNE
    return (unsigned short)(u >> 16);
}

// Fragment-major packed weights (1 KB per cell = 64 lanes x 16 B):
//   Wepk[nb=16][kc=32][lane=q*16+n][e=8] = bf16(We[kc*32+q*8+e][nb*16+n])
//   Wdpk[nb=64][kc= 8][lane=q*16+n][e=8] = bf16(Wd[kc*32+q*8+e][nb*16+n])
// hdr: [0..63] mse cells, [64..127] pair cells, [128] pair ticket,
//      [129] nP (int), [130] nR (int)

// ---------------------------------------------------------------------------
// prep: coalesced packing (unchanged). 256 blocks x 256 thr.
// ---------------------------------------------------------------------------
__global__ __launch_bounds__(256) void prep_kernel(
    const float* __restrict__ We, const float* __restrict__ Wd,
    unsigned short* __restrict__ Wepk, unsigned short* __restrict__ Wdpk,
    float* __restrict__ hdr) {
    const int b = blockIdx.x, t = threadIdx.x;
    if (b == 0 && t < 192) hdr[t] = 0.f;
    if (b < 128) {
        const int k0 = b, c = t;                       // k rows 8*k0..8*k0+7
        const int kc = k0 >> 2, q = k0 & 3, nb = c >> 4, li = c & 15;
        us8 v;
#pragma unroll
        for (int e = 0; e < 8; e++)
            v[e] = f2bf(We[(size_t)(k0 * 8 + e) * NH + c]);
        *(us8*)&Wepk[((size_t)(nb * 32 + kc)) * 512 + (q * 16 + li) * 8] = v;
    } else {
        const int idx = b - 128;
        const int k0 = idx >> 2, c = (idx & 3) * 256 + t;
        const int kc = k0 >> 2, q = k0 & 3, nb = c >> 4, li = c & 15;
        us8 v;
#pragma unroll
        for (int e = 0; e < 8; e++)
            v[e] = f2bf(Wd[(size_t)(k0 * 8 + e) * NF + c]);
        *(us8*)&Wdpk[((size_t)(nb * 8 + kc)) * 512 + (q * 16 + li) * 8] = v;
    }
}

// ---------------------------------------------------------------------------
// FUSED (R11): grid 256 x 512 thr (8 waves), 64 m-rows/block.
// R11 = register-pressure fit. LESSONS: gfx950 unified VGPR/AGPR file ->
// the 128-reg budget INCLUDES MFMA accumulators (R10 recount: gb64 + a2-64
// + af16 + xr64 ~ 200 regs -> 36MB spill, fused 66us). VGPR_Count pinned at
// 128 across 3 launch_bounds variants -> treat 128 as fixed, FIT within it.
// Changes vs R5 (best measured, 52.6us with 9MB spill):
// (a) fb prefetch depth 8 -> 4 (-32 regs). Weights are L2-resident after
//     first block per XCD (1MB vs 4MB L2) -> ~200cyc, depth 4 ~ covers.
// (b) phase 2: 2x512 -> 4x256-col passes: gb[4][2]+a2[4][2] (-64 regs).
//     MSE X-read inline (R10's xr[4][4] prefetch dropped: +64 regs was
//     the main R10 regression).
// (c) single-buffer xa, 2 barriers/quarter (R5 structure; R10 dbuf showed
//     no benefit and doubled LDS).
// Phase-1 live ~120, phase-2 live ~100 < 128 -> ZERO spill predicted
// (WRITE_SIZE < 1MB is the signature to check).
// ---------------------------------------------------------------------------
__global__ __launch_bounds__(512) void fused_kernel(
    const float* __restrict__ X,
    const unsigned short* __restrict__ Wepk, const unsigned short* __restrict__ Wdpk,
    const float* __restrict__ be, const float* __restrict__ bd,
    const float* __restrict__ Wc, const int* __restrict__ s, const int* __restrict__ pv,
    float* __restrict__ cP, float* __restrict__ cR, float* __restrict__ hdr) {
    __shared__ union {
        unsigned short xa[16384];        // 32 KB: X quarter, fragment-major
        struct {
            unsigned short gs[16384];    // 32 KB: g tile, fragment-major
            float credu[8][64];
            float msred[8];
        } p2;
    } u;
    const int t = threadIdx.x;
    const int b = blockIdx.x, m0 = b * 64;
    const int w = t >> 6, lane = t & 63, q = lane >> 4, li = lane & 15;

    // staging geometry: wave w stages rows w*8..w*8+7; lane reads 16B at
    // col lane*4 (global contiguous 1KB per wave-row).
    // LDS cell (kcgl = lane>>3, mi = r>>4); slot s = sq2*16+(r&15), p = s^kcgl.
    const int srow = w * 8;
    const int kcgl = lane >> 3;          // cell k-col 0..7
    const int sq2  = (lane >> 1) & 3;    // fragment q of this 16B
    const int sh   = lane & 1;           // element half

    // ---------------- stage quarter 0 --------------------------------------
    {
        const float* xq = X + (size_t)m0 * NF + lane * 4;
#pragma unroll
        for (int rr = 0; rr < 8; ++rr) {
            const int r = srow + rr;
            float4 v4 = *(const float4*)(xq + (size_t)r * NF);
            ushort4 st = { f2bf(v4.x), f2bf(v4.y), f2bf(v4.z), f2bf(v4.w) };
            const int p = (sq2 * 16 + (r & 15)) ^ kcgl;
            *(ushort4*)&u.xa[(kcgl * 4 + (r >> 4)) * 512 + p * 8 + sh * 4] = st;
        }
    }
    __syncthreads();

    // ---------------- phase 1: X @ We (4-deep B prefetch) -------------------
    const unsigned short* Bp[2];
#pragma unroll
    for (int j = 0; j < 2; j++)
        Bp[j] = Wepk + ((size_t)(w * 2 + j) * 32) * 512 + lane * 8;

    us8 fb[4][2];
#pragma unroll
    for (int z = 0; z < 4; ++z)
#pragma unroll
        for (int j = 0; j < 2; j++) fb[z][j] = *(const us8*)(Bp[j] + z * 512);

    f32x4 acc[4][2] = {};

#pragma unroll
    for (int ks = 0; ks < 4; ++ks) {
        float4 xn[8];
        // T14 issue-early: next quarter's X loads hidden under MFMA work.
        if (ks < 3) {
#pragma unroll
            for (int rr = 0; rr < 8; ++rr)
                xn[rr] = *(const float4*)(X + (size_t)(m0 + srow + rr) * NF +
                                          (ks + 1) * 256 + lane * 4);
        }
#pragma unroll
        for (int kcl = 0; kcl < 8; ++kcl) {
            const int kcg = ks * 8 + kcl;
            const int cb = kcg & 3;
#pragma unroll
            for (int mi = 0; mi < 4; ++mi) {
                bf16x8 a = __builtin_bit_cast(bf16x8,
                    *(const us8*)&u.xa[(kcl * 4 + mi) * 512 + (lane ^ kcl) * 8]);
                acc[mi][0] = __builtin_amdgcn_mfma_f32_16x16x32_bf16(
                    __builtin_bit_cast(bf16x8, fb[cb][0]), a, acc[mi][0], 0, 0, 0);
                acc[mi][1] = __builtin_amdgcn_mfma_f32_16x16x32_bf16(
                    __builtin_bit_cast(bf16x8, fb[cb][1]), a, acc[mi][1], 0, 0, 0);
            }
            if (kcg + 4 < 32) {
#pragma unroll
                for (int j = 0; j < 2; j++) fb[cb][j] = *(const us8*)(Bp[j] + (kcg + 4) * 512);
            }
        }
        __syncthreads();          // all waves done reading this quarter
        if (ks < 3) {             // write-late: regs -> LDS, re-barrier
#pragma unroll
            for (int rr = 0; rr < 8; ++rr) {
                const int r = srow + rr;
                ushort4 st = { f2bf(xn[rr].x), f2bf(xn[rr].y),
                               f2bf(xn[rr].z), f2bf(xn[rr].w) };
                const int p = (sq2 * 16 + (r & 15)) ^ kcgl;
                *(ushort4*)&u.xa[(kcgl * 4 + (r >> 4)) * 512 + p * 8 + sh * 4] = st;
            }
            __syncthreads();
        }
    }

    // epilogue: g -> fragment-major gs + critic partials (wave cols = cell w)
#pragma unroll
    for (int mi = 0; mi < 4; ++mi) {
        float csum = 0.f;
#pragma unroll
        for (int j = 0; j < 2; ++j) {
            const int colb = w * 32 + j * 16 + q * 4;
            float4 be4 = *(const float4*)&be[colb];
            float4 wc4 = *(const float4*)&Wc[colb];
            float v0 = acc[mi][j][0] + be4.x;
            float v1 = acc[mi][j][1] + be4.y;
            float v2 = acc[mi][j][2] + be4.z;
            float v3 = acc[mi][j][3] + be4.w;
            csum += v0 * wc4.x + v1 * wc4.y + v2 * wc4.z + v3 * wc4.w;
            ushort4 st = { f2bf(v0), f2bf(v1), f2bf(v2), f2bf(v3) };
            const int q2e = j * 2 + (q >> 1);
            const int p = (q2e * 16 + li) ^ w;
            *(ushort4*)&u.p2.gs[(w * 4 + mi) * 512 + p * 8 + (q & 1) * 4] = st;
        }
        csum += __shfl_down(csum, 32);
        csum += __shfl_down(csum, 16);
        if (lane < 16) u.p2.credu[w][mi * 16 + lane] = csum;
    }
    __syncthreads();   // gs + credu ready

    // in-block compaction of this block's 64 critic values (wave 0)
    if (t < 64) {
        float cs = 0.f;
#pragma unroll
        for (int ww = 0; ww < 8; ++ww) cs += u.p2.credu[ww][t];
        bool pr = (s[m0 + t] == pv[0]);
        unsigned long long mk = __ballot(pr);
        int np = __popcll(mk);
        int baseP = 0, baseR = 0;
        if (t == 0) {
            baseP = atomicAdd((int*)hdr + 129, np);
            baseR = atomicAdd((int*)hdr + 130, 64 - np);
        }
        baseP = __shfl(baseP, 0);
        baseR = __shfl(baseR, 0);
        int offP = __popcll(mk & ((1ull << t) - 1ull));
        int offR = t - offP;
        if (pr) cP[baseP + offP] = cs; else cR[baseR + offR] = cs;
    }

    // ---------------- phase 2: g @ Wd + MSE (4 passes x 256 cols) -----------
    float lsum = 0.f;
    const unsigned short* Wp = Wdpk + lane * 8;
#pragma unroll
    for (int pass = 0; pass < 4; ++pass) {
        const int nb0 = pass * 16 + w * 2;     // 2 n-blocks of 16 per wave
        us8 gb[4][2];
#pragma unroll
        for (int z = 0; z < 4; ++z)
#pragma unroll
            for (int j = 0; j < 2; ++j)
                gb[z][j] = *(const us8*)(Wp + ((size_t)((nb0 + j) * 8 + z)) * 512);
        f32x4 a2[4][2] = {};
#pragma unroll
        for (int kc = 0; kc < 8; ++kc) {
            const int cb = kc & 3;
#pragma unroll
            for (int mi = 0; mi < 4; ++mi) {
                bf16x8 af = __builtin_bit_cast(bf16x8,
                    *(const us8*)&u.p2.gs[(kc * 4 + mi) * 512 + (lane ^ kc) * 8]);
                a2[mi][0] = __builtin_amdgcn_mfma_f32_16x16x32_bf16(
                    __builtin_bit_cast(bf16x8, gb[cb][0]), af, a2[mi][0], 0, 0, 0);
                a2[mi][1] = __builtin_amdgcn_mfma_f32_16x16x32_bf16(
                    __builtin_bit_cast(bf16x8, gb[cb][1]), af, a2[mi][1], 0, 0, 0);
            }
            if (kc + 4 < 8) {
#pragma unroll
                for (int j = 0; j < 2; ++j)
                    gb[cb][j] = *(const us8*)(Wp + ((size_t)((nb0 + j) * 8 + kc + 4)) * 512);
            }
        }
        // MSE epilogue for this 256-col pass (X re-read inline, L3-warm)
#pragma unroll
        for (int mi = 0; mi < 4; ++mi) {
            const size_t rowoff = (size_t)(m0 + mi * 16 + li) * NF;
#pragma unroll
            for (int j = 0; j < 2; ++j) {
                const int colb = pass * 256 + w * 32 + j * 16 + q * 4;
                float4 bd4 = *(const float4*)&bd[colb];
                float4 xr  = *(const float4*)&X[rowoff + colb];
                float d0 = a2[mi][j][0] + bd4.x - xr.x;
                float d1 = a2[mi][j][1] + bd4.y - xr.y;
                float d2 = a2[mi][j][2] + bd4.z - xr.z;
                float d3 = a2[mi][j][3] + bd4.w - xr.w;
                lsum += d0 * d0 + d1 * d1 + d2 * d2 + d3 * d3;
            }
        }
    }
#pragma unroll
    for (int o = 32; o; o >>= 1) lsum += __shfl_down(lsum, o);
    if (lane == 0) u.p2.msred[w] = lsum;
    __syncthreads();
    if (t == 0) {
        float ms = 0.f;
#pragma unroll
        for (int ww = 0; ww < 8; ++ww) ms += u.p2.msred[ww];
        atomicAdd(&hdr[b & 63], ms);
    }
}

// ---------------------------------------------------------------------------
// compacted pairwise L1 + fused finalize (last-ticket block writes d_out)
// grid (16 j-chunks x 32 i-chunks of 512)
// ---------------------------------------------------------------------------
__global__ __launch_bounds__(256) void pair_fin_kernel(
    const float* __restrict__ cP, const float* __restrict__ cR,
    float* __restrict__ hdr, float* __restrict__ out) {
    __shared__ float sj[1024];
    __shared__ float red[256];
    __shared__ int win;
    const int nP = ((const int*)hdr)[129];
    const int nR = ((const int*)hdr)[130];
    const int jb = blockIdx.x * 1024;
    int jn = nR - jb; if (jn < 0) jn = 0; if (jn > 1024) jn = 1024;
    float sum = 0.f;
    if (jn > 0 && blockIdx.y * 512 < nP) {
        for (int j = threadIdx.x; j < 1024; j += 256)
            sj[j] = (jb + j < nR) ? cR[jb + j] : 0.f;
        __syncthreads();
        const int a0 = blockIdx.y * 512 + threadIdx.x, a1 = a0 + 256;
        const float ca0 = (a0 < nP) ? cP[a0] : 0.f;
        const float ca1 = (a1 < nP) ? cP[a1] : 0.f;
        float s0 = 0.f, s1 = 0.f;
#pragma unroll 8
        for (int j4 = 0; j4 < 256; j4++) {
            float4 v = *(const float4*)&sj[j4 * 4];
            s0 += fabsf(ca0 - v.x) + fabsf(ca0 - v.y) + fabsf(ca0 - v.z) + fabsf(ca0 - v.w);
            s1 += fabsf(ca1 - v.x) + fabsf(ca1 - v.y) + fabsf(ca1 - v.z) + fabsf(ca1 - v.w);
        }
        float pad = (float)(1024 - jn);
        s0 -= pad * fabsf(ca0);
        s1 -= pad * fabsf(ca1);
        if (a0 >= nP) s0 = 0.f;
        if (a1 >= nP) s1 = 0.f;
        sum = s0 + s1;
#pragma unroll
        for (int o = 32; o; o >>= 1) sum += __shfl_down(sum, o);
        if ((threadIdx.x & 63) == 0 && sum != 0.f)
            atomicAdd(&hdr[64 + ((blockIdx.y * 16 + blockIdx.x) & 63)], sum);
    }
    __threadfence();
    __syncthreads();
    if (threadIdx.x == 0)
        win = (atomicAdd((int*)(hdr + 128), 1) == 16 * 32 - 1) ? 1 : 0;
    __syncthreads();
    if (win) {
        float v = (threadIdx.x < 128) ? atomicAdd(&hdr[threadIdx.x], 0.f) : 0.f;
        red[threadIdx.x] = v;
        __syncthreads();
        if (threadIdx.x == 0) {
            float ms = 0.f, ps = 0.f;
            for (int i = 0; i < 64; i++) { ms += red[i]; ps += red[64 + i]; }
            int np = atomicAdd((int*)(hdr + 129), 0);
            out[0] = ms / (float)((size_t)NR * NF);
            out[1] = (float)NR;
            out[2] = ps / (float)np;
            out[3] = (float)np;
        }
    }
}

extern "C" void kernel_launch(void* const* d_in, const int* in_sizes, int n_in,
                              void* d_out, int out_size, void* d_ws, size_t ws_size,
                              hipStream_t stream) {
    const float* X  = (const float*)d_in[0];
    const float* We = (const float*)d_in[1];
    const float* be = (const float*)d_in[2];
    const float* Wd = (const float*)d_in[3];
    const float* bd = (const float*)d_in[4];
    const float* Wc = (const float*)d_in[5];
    // bc (d_in[6]) omitted: cancels in |c_i - c_j|
    const int*   s  = (const int*)d_in[7];
    const int*   pv = (const int*)d_in[8];

    char* ws = (char*)d_ws;
    float* hdr = (float*)ws;                                     // 192 f
    float* cP  = (float*)(ws + 1024);                            // 64 KB
    float* cR  = (float*)(ws + 1024 + 65536);                    // 64 KB
    unsigned short* Wepk = (unsigned short*)(ws + 1024 + 2 * 65536);  // 512 KB
    unsigned short* Wdpk = Wepk + (size_t)NH * NF;                    // 512 KB

    prep_kernel<<<256, 256, 0, stream>>>(We, Wd, Wepk, Wdpk, hdr);
    fused_kernel<<<256, 512, 0, stream>>>(X, Wepk, Wdpk, be, bd, Wc, s, pv, cP, cR, hdr);
    pair_fin_kernel<<<dim3(16, 32), 256, 0, stream>>>(cP, cR, hdr, (float*)d_out);
}